// Round 5
// baseline (572.352 us; speedup 1.0000x reference)
//
#include <hip/hip_runtime.h>
#include <hip/hip_bf16.h>

typedef __attribute__((ext_vector_type(8))) short bf16x8;
typedef __attribute__((ext_vector_type(4))) float f32x4;

#define HID 512
#define NB 32
#define SEQL 4096
#define NKC 16          // 512/32 k-chunks
#define NBLK 2048       // 131072 rows / 64 per block (4 waves x 16 rows)

// workspace layout (bytes)
#define WS_BP    0                      // packed bf16 W_enc: 512 KB
#define WS_DPROJ (512*1024)             // fp32 32x512: 64 KB
#define WS_PC    (576*1024)             // per-block ctx partials: 2048x512 f32 = 4 MB
#define WS_PCS   (576*1024 + 4*1024*1024) // per-block expsum partials: 2048 f32

__device__ __forceinline__ short f2bf(float f) {
    unsigned u = __float_as_uint(f);
    unsigned r = (u + 0x7fffu + ((u >> 16) & 1u)) >> 16;   // RNE
    return (short)r;
}

__device__ __forceinline__ float fast_tanh(float x) {
    float e = __expf(2.0f * x);
    float r = __builtin_amdgcn_rcpf(e + 1.0f);
    return 1.0f - 2.0f * r;
}

// ---------------------------------------------------------------------------
// K_pre: (a) W_enc pack fp32->bf16 B-frag layout [blk 0..127],
// (b) dproj GEMV, 8-way h-parallel [blk 128..639]
// ---------------------------------------------------------------------------
__global__ void k_pre(const float* __restrict__ We, short* __restrict__ Bp,
                      const float* __restrict__ dec, const float* __restrict__ Wd,
                      const float* __restrict__ be, const float* __restrict__ bd,
                      float* __restrict__ dproj) {
    const int blk = blockIdx.x, t = threadIdx.x;
    if (blk < 128) {
        // Bp[kc][nt][lane][j] = We[kc*32 + (lane>>4)*8 + j][nt*16 + (lane&15)]
        int tid  = blk * 256 + t;
        int lane = tid & 63;
        int nt   = (tid >> 6) & 31;
        int kc   = tid >> 11;
        int k0   = kc * 32 + (lane >> 4) * 8;
        int n    = nt * 16 + (lane & 15);
        bf16x8 v;
#pragma unroll
        for (int j = 0; j < 8; ++j) v[j] = f2bf(We[(size_t)(k0 + j) * HID + n]);
        *(bf16x8*)&Bp[(size_t)tid * 8] = v;
    } else {
        __shared__ float red[8][33];
        int bid2 = blk - 128;
        int b  = bid2 >> 4, kg = bid2 & 15;     // 32 batches x 16 k-groups
        int kl = t & 31,    hc = t >> 5;        // 32 k-cols x 8 h-chunks
        int k  = kg * 32 + kl;
        const float* dr = dec + (size_t)b * HID;
        float a = 0.f;
#pragma unroll 8
        for (int j = 0; j < 64; ++j) {
            int h = hc * 64 + j;
            a += dr[h] * Wd[(size_t)h * HID + k];
        }
        red[hc][kl] = a;
        __syncthreads();
        if (hc == 0) {
            float s = be[k] + bd[k];
#pragma unroll
            for (int c = 0; c < 8; ++c) s += red[c][kl];
            dproj[(size_t)b * HID + k] = s;
        }
    }
}

// ---------------------------------------------------------------------------
// K_main: wave-autonomous. Each wave owns 16 rows:
//   - A-frags (16 rows x 512 K, bf16) held in 64 VGPRs, loaded once from E.
//   - Col-group loop (16 x 32 cols): acc[2] only; fold tanh*Wv into 4 score
//     partials after each group -> tiny register footprint -> 16 waves/CU.
//   - B frags streamed from L2/L1 (all waves sweep identical addresses).
//   - NO LDS / barriers in compute; one tail barrier for block partial-reduce.
// Block = 4 waves = 64 rows. Partials (ctx 512 + expsum) -> workspace.
// ---------------------------------------------------------------------------
__global__ __launch_bounds__(256, 4)
void k_main(const float* __restrict__ E, const short* __restrict__ Bp,
            const float* __restrict__ dproj, const float* __restrict__ Wv,
            float* __restrict__ outw, float* __restrict__ pc,
            float* __restrict__ pcs) {
    __shared__ float ctxs[4][HID];   // 8 KB
    __shared__ float ssum[4];

    const int tid  = threadIdx.x;
    const int wave = tid >> 6, lane = tid & 63;
    const int quad = lane >> 4, l15 = lane & 15;
    const int bid  = blockIdx.x;
    const int row0 = bid * 64 + wave * 16;   // this wave's 16 rows
    const int b    = bid >> 6;               // 64 blocks per batch

    // ---- load A-frags: fa[kc] lane-> A[m=l15][k=kc*32+quad*8+j], fp32->bf16 ----
    const float* ap = E + (size_t)(row0 + l15) * HID + quad * 8;
    bf16x8 fa[NKC];
#pragma unroll
    for (int kc = 0; kc < NKC; ++kc) {
        float4 a0 = *(const float4*)(ap + kc * 32);
        float4 a1 = *(const float4*)(ap + kc * 32 + 4);
        bf16x8 v;
        v[0] = f2bf(a0.x); v[1] = f2bf(a0.y); v[2] = f2bf(a0.z); v[3] = f2bf(a0.w);
        v[4] = f2bf(a1.x); v[5] = f2bf(a1.y); v[6] = f2bf(a1.z); v[7] = f2bf(a1.w);
        fa[kc] = v;
    }

    // ---- col-group loop: 16 groups x 32 cols (2 MFMA col-tiles each) ----
    const short* bbl = Bp + (size_t)lane * 8;     // lane base into frag tiles
    const float* dp  = dproj + (size_t)b * HID;
    float sp[4] = {0.f, 0.f, 0.f, 0.f};           // score partials, rows quad*4+g

    for (int cg = 0; cg < 16; ++cg) {
        f32x4 a0 = (f32x4){0.f, 0.f, 0.f, 0.f};
        f32x4 a1 = (f32x4){0.f, 0.f, 0.f, 0.f};
        const short* bcg = bbl + (size_t)(cg * 2) * 512;   // nt = cg*2
#pragma unroll
        for (int kc = 0; kc < NKC; ++kc) {
            bf16x8 fb0 = *(const bf16x8*)(bcg + (size_t)kc * 16384);
            bf16x8 fb1 = *(const bf16x8*)(bcg + (size_t)kc * 16384 + 512);
            a0 = __builtin_amdgcn_mfma_f32_16x16x32_bf16(fa[kc], fb0, a0, 0, 0, 0);
            a1 = __builtin_amdgcn_mfma_f32_16x16x32_bf16(fa[kc], fb1, a1, 0, 0, 0);
        }
        // fold: cols cg*32 + {0,1}*16 + l15 ; rows quad*4+g
        int c0 = cg * 32 + l15;
        float dv0 = dp[c0],      wv0 = Wv[c0];
        float dv1 = dp[c0 + 16], wv1 = Wv[c0 + 16];
#pragma unroll
        for (int g = 0; g < 4; ++g) {
            sp[g] += fast_tanh(a0[g] + dv0) * wv0;
            sp[g] += fast_tanh(a1[g] + dv1) * wv1;
        }
    }

    // ---- wave-local softmax numerators ----
#pragma unroll
    for (int g = 0; g < 4; ++g) {
        float v = sp[g];
        v += __shfl_xor(v, 1); v += __shfl_xor(v, 2);
        v += __shfl_xor(v, 4); v += __shfl_xor(v, 8);
        sp[g] = v;            // row (quad*4+g) sum, replicated in the quad
    }
    float pv[4];
#pragma unroll
    for (int g = 0; g < 4; ++g) pv[g] = __expf(sp[g]);  // b_v cancels in softmax
    if (l15 == 0) {
#pragma unroll
        for (int g = 0; g < 4; ++g) outw[row0 + quad * 4 + g] = pv[g];
    }
    float ws = pv[0] + pv[1] + pv[2] + pv[3];
    ws += __shfl_xor(ws, 16); ws += __shfl_xor(ws, 32);   // sum over quads
    if (lane == 0) ssum[wave] = ws;

    // ---- context partial: 16 rows, lane covers h = lane*8..+8 ----
    float pvr[16];
#pragma unroll
    for (int r = 0; r < 16; ++r) pvr[r] = __shfl(pv[r & 3], (r >> 2) * 16);
    const float* er = E + (size_t)row0 * HID + lane * 8;
    f32x4 c0 = (f32x4){0.f, 0.f, 0.f, 0.f};
    f32x4 c1 = (f32x4){0.f, 0.f, 0.f, 0.f};
#pragma unroll
    for (int r = 0; r < 16; ++r) {
        float4 e0 = *(const float4*)(er + (size_t)r * HID);
        float4 e1 = *(const float4*)(er + (size_t)r * HID + 4);
        float w = pvr[r];
        c0.x += w * e0.x; c0.y += w * e0.y; c0.z += w * e0.z; c0.w += w * e0.w;
        c1.x += w * e1.x; c1.y += w * e1.y; c1.z += w * e1.z; c1.w += w * e1.w;
    }
    *(f32x4*)&ctxs[wave][lane * 8]     = c0;
    *(f32x4*)&ctxs[wave][lane * 8 + 4] = c1;
    __syncthreads();   // the only block barrier

    // ---- block partial-reduce -> workspace (no atomics) ----
    if (tid < 128) {   // 128 threads x 4 floats = 512
        int h = tid * 4;
        f32x4 s = *(f32x4*)&ctxs[0][h];
        f32x4 s1 = *(f32x4*)&ctxs[1][h];
        f32x4 s2 = *(f32x4*)&ctxs[2][h];
        f32x4 s3 = *(f32x4*)&ctxs[3][h];
        s.x += s1.x + s2.x + s3.x; s.y += s1.y + s2.y + s3.y;
        s.z += s1.z + s2.z + s3.z; s.w += s1.w + s2.w + s3.w;
        *(f32x4*)&pc[(size_t)bid * HID + h] = s;
    }
    if (tid == 0) pcs[bid] = ssum[0] + ssum[1] + ssum[2] + ssum[3];
}

// ---------------------------------------------------------------------------
// K_finish: per batch b (32 blocks): total = sum of 64 block expsums;
// ctx[b][h] = sum_w pc[w][h] / total; weights[b][s] /= total.
// ---------------------------------------------------------------------------
__global__ void k_finish(float* __restrict__ out, const float* __restrict__ pc,
                         const float* __restrict__ pcs) {
    __shared__ float red[64];
    const int b = blockIdx.x, t = threadIdx.x;
    if (t < 64) red[t] = pcs[b * 64 + t];
    __syncthreads();
    if (t < 16) {
        float s = red[t] + red[t + 16] + red[t + 32] + red[t + 48];
        red[t] = s;
    }
    __syncthreads();
    float total = 0.f;
#pragma unroll
    for (int i = 0; i < 16; ++i) total += red[i];
    float rs = 1.0f / total;

    // context: h = t, t+256
    const float* pcb = pc + (size_t)b * 64 * HID;
#pragma unroll
    for (int hh = 0; hh < 2; ++hh) {
        int h = t + hh * 256;
        float a = 0.f;
#pragma unroll 8
        for (int w = 0; w < 64; ++w) a += pcb[(size_t)w * HID + h];
        out[(size_t)b * HID + h] = a * rs;
    }
    // weights
    float* ow = out + (size_t)NB * HID + (size_t)b * SEQL;
    for (int i = t; i < SEQL; i += 256)
        ow[i] *= rs;
}

extern "C" void kernel_launch(void* const* d_in, const int* in_sizes, int n_in,
                              void* d_out, int out_size, void* d_ws, size_t ws_size,
                              hipStream_t stream) {
    const float* E   = (const float*)d_in[0];
    const float* dec = (const float*)d_in[1];
    const float* We  = (const float*)d_in[2];
    const float* be  = (const float*)d_in[3];
    const float* Wd  = (const float*)d_in[4];
    const float* bd  = (const float*)d_in[5];
    const float* Wv  = (const float*)d_in[6];
    // d_in[7] = b_v: uniform shift per score -> cancels in softmax
    float* out = (float*)d_out;
    char*  ws  = (char*)d_ws;
    short* Bp    = (short*)(ws + WS_BP);
    float* dproj = (float*)(ws + WS_DPROJ);
    float* pc    = (float*)(ws + WS_PC);
    float* pcs   = (float*)(ws + WS_PCS);
    float* outw  = out + (size_t)NB * HID;    // weights region of d_out

    k_pre<<<640, 256, 0, stream>>>(We, Bp, dec, Wd, be, bd, dproj);
    k_main<<<NBLK, 256, 0, stream>>>(E, Bp, dproj, Wv, outw, pc, pcs);
    k_finish<<<NB, 256, 0, stream>>>(out, pc, pcs);
}